// Round 1
// baseline (269.461 us; speedup 1.0000x reference)
//
#include <hip/hip_runtime.h>
#include <math.h>

// Problem constants (fixed by setup_inputs): B=16, T=4096, D=512, fp32.
#define BB 16
#define TT 4096
#define DD 512
#define D4 128   // DD / 4 (float4 columns)

__device__ __forceinline__ float sigmf(float v) {
    return 1.0f / (1.0f + expf(-v));
}

// K1: per-(b, chunk) local scan with zero init (chunk 0: exact init s_{-1}=x0),
// writes only the chunk-end value E_c to `ends`.
// Block: 256 threads = 2 b-rows x 128 float4 columns. Grid: (C, BB/2).
__global__ __launch_bounds__(256) void es_chunk_ends(
    const float* __restrict__ x, const float* __restrict__ alpha,
    float* __restrict__ ends, int C, int L)
{
    const int c   = blockIdx.x;
    const int tid = threadIdx.x;
    const int b   = (blockIdx.y << 1) + (tid >> 7);
    const int d4  = tid & 127;

    const float4 al = reinterpret_cast<const float4*>(alpha)[d4];
    const float ax = sigmf(al.x), ay = sigmf(al.y), az = sigmf(al.z), aw = sigmf(al.w);
    const float fx = 1.0f - ax, fy = 1.0f - ay, fz = 1.0f - az, fw = 1.0f - aw;

    const float4* xp = reinterpret_cast<const float4*>(x)
                     + ((size_t)b * TT + (size_t)c * L) * D4 + d4;

    float4 s;
    if (c == 0) {
        s = xp[0];                       // virtual s_{-1} = x_0 -> chunk 0 end is exact
    } else {
        s.x = s.y = s.z = s.w = 0.0f;    // zero-init local scan
    }

    #pragma unroll 8
    for (int i = 0; i < L; ++i) {
        const float4 v = xp[(size_t)i * D4];
        s.x = fmaf(ax, v.x, fx * s.x);
        s.y = fmaf(ay, v.y, fy * s.y);
        s.z = fmaf(az, v.z, fz * s.z);
        s.w = fmaf(aw, v.w, fw * s.w);
    }

    reinterpret_cast<float4*>(ends)[((size_t)b * C + c) * D4 + d4] = s;
}

// K2: carry scan across chunks, in place: S_c = E_c + (1-a)^L * S_{c-1}.
// 2048 threads total (one per (b, d4)); 8-deep prefetch to hide load latency.
__global__ __launch_bounds__(256) void es_carry_scan(
    float* __restrict__ ends, const float* __restrict__ alpha, int C, int L)
{
    const int g  = blockIdx.x * 256 + threadIdx.x;   // 0..2047
    const int b  = g >> 7;
    const int d4 = g & 127;

    const float4 al = reinterpret_cast<const float4*>(alpha)[d4];
    const float ax = sigmf(al.x), ay = sigmf(al.y), az = sigmf(al.z), aw = sigmf(al.w);
    float4 fL;
    fL.x = powf(1.0f - ax, (float)L);
    fL.y = powf(1.0f - ay, (float)L);
    fL.z = powf(1.0f - az, (float)L);
    fL.w = powf(1.0f - aw, (float)L);

    float4* e = reinterpret_cast<float4*>(ends) + (size_t)b * C * D4 + d4;

    float4 S = e[0];   // S_0 = E_0 (already exact)
    int c = 1;
    for (; c + 8 <= C; c += 8) {
        float4 v[8];
        #pragma unroll
        for (int j = 0; j < 8; ++j) v[j] = e[(size_t)(c + j) * D4];
        #pragma unroll
        for (int j = 0; j < 8; ++j) {
            S.x = fmaf(fL.x, S.x, v[j].x);
            S.y = fmaf(fL.y, S.y, v[j].y);
            S.z = fmaf(fL.z, S.z, v[j].z);
            S.w = fmaf(fL.w, S.w, v[j].w);
            e[(size_t)(c + j) * D4] = S;
        }
    }
    for (; c < C; ++c) {
        const float4 v = e[(size_t)c * D4];
        S.x = fmaf(fL.x, S.x, v.x);
        S.y = fmaf(fL.y, S.y, v.y);
        S.z = fmaf(fL.z, S.z, v.z);
        S.w = fmaf(fL.w, S.w, v.w);
        e[(size_t)c * D4] = S;
    }
}

// K3: re-read x, start each chunk from the exact carry S_{c-1}, write output.
__global__ __launch_bounds__(256) void es_final(
    const float* __restrict__ x, const float* __restrict__ alpha,
    const float* __restrict__ finals, float* __restrict__ out, int C, int L)
{
    const int c   = blockIdx.x;
    const int tid = threadIdx.x;
    const int b   = (blockIdx.y << 1) + (tid >> 7);
    const int d4  = tid & 127;

    const float4 al = reinterpret_cast<const float4*>(alpha)[d4];
    const float ax = sigmf(al.x), ay = sigmf(al.y), az = sigmf(al.z), aw = sigmf(al.w);
    const float fx = 1.0f - ax, fy = 1.0f - ay, fz = 1.0f - az, fw = 1.0f - aw;

    const size_t base = ((size_t)b * TT + (size_t)c * L) * D4 + d4;
    const float4* xp = reinterpret_cast<const float4*>(x) + base;
    float4*       op = reinterpret_cast<float4*>(out) + base;

    float4 s;
    if (c == 0) {
        s = xp[0];                                   // s_{-1} = x_0
    } else {
        s = reinterpret_cast<const float4*>(finals)[((size_t)b * C + (c - 1)) * D4 + d4];
    }

    #pragma unroll 8
    for (int i = 0; i < L; ++i) {
        const float4 v = xp[(size_t)i * D4];
        s.x = fmaf(ax, v.x, fx * s.x);
        s.y = fmaf(ay, v.y, fy * s.y);
        s.z = fmaf(az, v.z, fz * s.z);
        s.w = fmaf(aw, v.w, fw * s.w);
        op[(size_t)i * D4] = s;
    }
}

// Fallback: full serial scan per (b, d4) column if ws is too small for chunking.
__global__ __launch_bounds__(256) void es_serial(
    const float* __restrict__ x, const float* __restrict__ alpha,
    float* __restrict__ out)
{
    const int g  = blockIdx.x * 256 + threadIdx.x;   // 0..2047
    const int b  = g >> 7;
    const int d4 = g & 127;

    const float4 al = reinterpret_cast<const float4*>(alpha)[d4];
    const float ax = sigmf(al.x), ay = sigmf(al.y), az = sigmf(al.z), aw = sigmf(al.w);
    const float fx = 1.0f - ax, fy = 1.0f - ay, fz = 1.0f - az, fw = 1.0f - aw;

    const float4* xp = reinterpret_cast<const float4*>(x) + (size_t)b * TT * D4 + d4;
    float4*       op = reinterpret_cast<float4*>(out) + (size_t)b * TT * D4 + d4;

    float4 s = xp[0];
    #pragma unroll 4
    for (int t = 0; t < TT; ++t) {
        const float4 v = xp[(size_t)t * D4];
        s.x = fmaf(ax, v.x, fx * s.x);
        s.y = fmaf(ay, v.y, fy * s.y);
        s.z = fmaf(az, v.z, fz * s.z);
        s.w = fmaf(aw, v.w, fw * s.w);
        op[(size_t)t * D4] = s;
    }
}

extern "C" void kernel_launch(void* const* d_in, const int* in_sizes, int n_in,
                              void* d_out, int out_size, void* d_ws, size_t ws_size,
                              hipStream_t stream)
{
    const float* x     = (const float*)d_in[0];
    const float* alpha = (const float*)d_in[1];
    float*       out   = (float*)d_out;

    // Pick chunk count C (pow2, >=8) so the carry buffer fits in workspace.
    int C = 128;
    while (C > 8 && (size_t)BB * C * DD * sizeof(float) > ws_size) C >>= 1;

    if ((size_t)BB * C * DD * sizeof(float) > ws_size) {
        // Workspace too small even for C=8: serial fallback (correct, slower).
        es_serial<<<dim3(8), 256, 0, stream>>>(x, alpha, out);
        return;
    }

    const int L = TT / C;
    float* ends = (float*)d_ws;

    es_chunk_ends<<<dim3(C, BB / 2), 256, 0, stream>>>(x, alpha, ends, C, L);
    es_carry_scan<<<dim3(8), 256, 0, stream>>>(ends, alpha, C, L);
    es_final<<<dim3(C, BB / 2), 256, 0, stream>>>(x, alpha, ends, out, C, L);
}